// Round 8
// baseline (5191.896 us; speedup 1.0000x reference)
//
#include <hip/hip_runtime.h>

#define NEDGE  500000
#define NTILE  7813        // ceil(NEDGE/64)
#define NCH    280         // chunks (divisible by 8 XCDs: 35 per XCD)
#define CHUNK  28          // tiles per chunk; 280*28 = 7840 >= 7813
#define NPAIR  14

typedef _Float16 v8h __attribute__((ext_vector_type(8)));
typedef float    v4f __attribute__((ext_vector_type(4)));

// PAIRS in natural k order
__constant__ int cI[14] = {0,0,1,1,0,1,1,2,2,2,3,3,3,3};
__constant__ int cJ[14] = {0,1,1,1,2,2,2,2,2,2,3,0,1,2};

// W1 (14,320,256) fp32 -> W1T fp16 in MFMA-B-fragment tile order:
// W1T[k14][nt(16)][kc(10)][quad(4)][col(16)][j(8)]
__global__ __launch_bounds__(256) void prep_w1(const float* __restrict__ W1,
                                               _Float16* __restrict__ W1T) {
    int tid = blockIdx.x * 256 + threadIdx.x;
    if (tid >= 14*320*256) return;
    int n   = tid & 255;
    int t   = tid >> 8;
    int kk  = t % 320;
    int k14 = t / 320;
    float v = W1[tid];
    int dst = ((((k14*16 + (n>>4))*10 + (kk>>5))*4 + ((kk>>3)&3))*16 + (n&15))*8 + (kk&7);
    W1T[dst] = (_Float16)v;
}

// Dynamic LDS (bytes):
//   [     0,  81920)  xbuf[2][64*320] f16  (double-buffered X tile, swizzled)
//   [ 81920, 114688)  part[2][64*64]  f32  (parity-buffered reduction scratch)
// X swizzle: 16B chunk ck at row -> ck' = (ck & ~7) | ((ck ^ row) & 7)
// part word addr = P*64 + (Q^col)*4 + r   (P = wn*16+col: n-col group 0..63,
//   Q = edge>>2, r = edge&3; XOR makes both write and read ~conflict-free)
//
// REGISTER BUDGET (hard-won, rounds 6/7): dynamic LDS is invisible at compile
// time, so the backend's occupancy heuristic targets 4 waves/EU -> 128-VGPR
// budget -> the 160-reg bfr array spills to scratch (WRITE_SIZE 6.5 GB,
// MfmaUtil 9%). __launch_bounds__' 2nd arg is only a MIN waves/EU and cannot
// lower that target. amdgpu_waves_per_eu(2,2) pins the range: 256-reg budget,
// matching the true occupancy (8-wave block, 1 block/CU from 112 KB LDS).
__global__ __launch_bounds__(512)
__attribute__((amdgpu_waves_per_eu(2, 2)))
void hopping_ws(
    const float* __restrict__ sfeat, const float* __restrict__ pfeat,
    const float* __restrict__ dfeat, const float* __restrict__ Sfeat,
    const int*  __restrict__ hop,   const float* __restrict__ darr,
    const float* __restrict__ exd,  const float* __restrict__ b1,
    const float* __restrict__ W2,   const float* __restrict__ b2,
    const _Float16* __restrict__ W1T, float* __restrict__ out)
{
    extern __shared__ char smem[];
    _Float16* xb0  = (_Float16*)smem;                 // 2 x 20480 halves
    float*    part = (float*)(smem + 81920);          // 2 x 4096 floats

    const int tid = threadIdx.x;          // 0..511
    const int bid = blockIdx.x;           // 0..3919

    const int xcd   = bid & 7;
    const int q     = bid >> 3;
    const int k14   = q % 14;
    const int chunk = xcd*35 + q/14;      // 0..279
    const long t0   = (long)chunk * CHUNK;
    int my_n = CHUNK;
    if (t0 + my_n > NTILE) my_n = (int)(NTILE - t0);   // always >= 1

    const int i4 = cI[k14], j4 = cJ[k14];
    const float* gt = (i4==0)?sfeat:(i4==1)?pfeat:(i4==2)?dfeat:Sfeat;
    const float* ht = (j4==0)?sfeat:(j4==1)?pfeat:(j4==2)?dfeat:Sfeat;

    const int lane = tid & 63;
    const int w    = tid >> 6;            // wave 0..7
    const int wm   = w >> 2;              // M half: rows [wm*32, wm*32+32)
    const int wn   = w & 3;               // N quarter: cols [wn*64, wn*64+64)
    const int col  = lane & 15;
    const int quad = lane >> 4;
    const int ser  = tid >> 3;            // staging row 0..63
    const int sq   = tid & 7;             // 8 threads per row

    // ---- resident B fragments: 4 nt x 10 kc x b128 = 160 VGPRs, loaded once ----
    v8h bfr[4][10];
    {
        const _Float16* wb = W1T + (size_t)k14 * 81920;
        #pragma unroll
        for (int nt = 0; nt < 4; ++nt)
            #pragma unroll
            for (int kc = 0; kc < 10; ++kc)
                bfr[nt][kc] = *(const v8h*)&wb[(((size_t)(wn*4+nt)*10 + kc)*64 + lane)*8];
    }
    float b1v[4], w2v[4];
    #pragma unroll
    for (int nt = 0; nt < 4; ++nt) {
        int n = (wn*4+nt)*16 + col;
        b1v[nt] = b1[k14*256 + n];
        w2v[nt] = W2[k14*256 + n];
    }
    const float b2v = b2[k14];

    // ---- staging state ----
    float4 sg[4], sh[4], sx[2]; float sinv = 0.f;
    int ca1, ca2; float cdv;      // hop data for tile (ti+1)
    int fa1, fa2; float fdv;      // hop data for tile (ti+2)

    auto hopload = [&](int ti, int& a1, int& a2, float& dv) {
        long eg = (t0 + ti)*64 + ser; if (eg >= NEDGE) eg = NEDGE - 1;
        a1 = hop[2*eg]; a2 = hop[2*eg + 1]; dv = darr[eg];
    };
    // issue g (atom1 feature) + ex loads: 64B contiguous per thread
    auto issue_gx = [&](int ti, int a1, float dv) {
        sinv = 1.0f / (dv * dv);
        const float4* s1 = (const float4*)gt + (size_t)a1 * 32;
        #pragma unroll
        for (int r = 0; r < 4; ++r) sg[r] = s1[sq*4 + r];
        long eg = (t0 + ti)*64 + ser; if (eg >= NEDGE) eg = NEDGE - 1;
        const float4* s3 = (const float4*)exd + eg * 16;
        sx[0] = s3[sq*2]; sx[1] = s3[sq*2 + 1];
    };
    auto issue_h = [&](int a2) {
        const float4* s2 = (const float4*)ht + (size_t)a2 * 32;
        #pragma unroll
        for (int r = 0; r < 4; ++r) sh[r] = s2[sq*4 + r];
    };
    auto write_gx = [&](_Float16* dst) {
        #pragma unroll
        for (int hf = 0; hf < 2; ++hf) {       // g chunks 2sq, 2sq+1
            float4 a = sg[hf*2], b = sg[hf*2+1];
            v8h hv;
            hv[0]=(_Float16)(a.x*sinv); hv[1]=(_Float16)(a.y*sinv);
            hv[2]=(_Float16)(a.z*sinv); hv[3]=(_Float16)(a.w*sinv);
            hv[4]=(_Float16)(b.x*sinv); hv[5]=(_Float16)(b.y*sinv);
            hv[6]=(_Float16)(b.z*sinv); hv[7]=(_Float16)(b.w*sinv);
            int ch = sq*2 + hf;
            int sz = (ch & ~7) | ((ch ^ ser) & 7);
            *(v8h*)&dst[ser*320 + sz*8] = hv;
        }
        {                                       // ex chunk 32+sq (no scaling)
            float4 a = sx[0], b = sx[1];
            v8h hv;
            hv[0]=(_Float16)a.x; hv[1]=(_Float16)a.y;
            hv[2]=(_Float16)a.z; hv[3]=(_Float16)a.w;
            hv[4]=(_Float16)b.x; hv[5]=(_Float16)b.y;
            hv[6]=(_Float16)b.z; hv[7]=(_Float16)b.w;
            int ch = 32 + sq;
            int sz = (ch & ~7) | ((ch ^ ser) & 7);
            *(v8h*)&dst[ser*320 + sz*8] = hv;
        }
    };
    auto write_h = [&](_Float16* dst) {
        #pragma unroll
        for (int hf = 0; hf < 2; ++hf) {       // h chunks 16+2sq, 16+2sq+1
            float4 a = sh[hf*2], b = sh[hf*2+1];
            v8h hv;
            hv[0]=(_Float16)(a.x*sinv); hv[1]=(_Float16)(a.y*sinv);
            hv[2]=(_Float16)(a.z*sinv); hv[3]=(_Float16)(a.w*sinv);
            hv[4]=(_Float16)(b.x*sinv); hv[5]=(_Float16)(b.y*sinv);
            hv[6]=(_Float16)(b.z*sinv); hv[7]=(_Float16)(b.w*sinv);
            int ch = 16 + sq*2 + hf;
            int sz = (ch & ~7) | ((ch ^ ser) & 7);
            *(v8h*)&dst[ser*320 + sz*8] = hv;
        }
    };

    // ---- prologue: fill buffer 0 for tile 0; prefetch hop for tile 1 ----
    {
        int a1, a2; float dv;
        hopload(0, a1, a2, dv);
        issue_gx(0, a1, dv);
        issue_h(a2);
        hopload(1, ca1, ca2, cdv);
        write_gx(xb0);
        write_h(xb0);
    }
    __syncthreads();

    #pragma unroll 1
    for (int ti = 0; ti < my_n; ++ti) {
        const int  cur = ti & 1;
        const bool hn  = (ti + 1 < my_n);
        const _Float16* xb  = xb0 + cur*20480;
        _Float16*       nxt = xb0 + (cur^1)*20480;

        // 1. issue next tile's g+ex gathers; prefetch hop(ti+2)
        if (hn)              issue_gx(ti+1, ca1, cdv);
        if (ti + 2 < my_n)   hopload(ti+2, fa1, fa2, fdv);

        v4f acc[2][4];
        #pragma unroll
        for (int a = 0; a < 2; ++a)
            #pragma unroll
            for (int b = 0; b < 4; ++b)
                acc[a][b] = (v4f){0.f,0.f,0.f,0.f};

        // 2. first K half (kc 0..4)
        #pragma unroll
        for (int kc = 0; kc < 5; ++kc) {
            v8h af[2];
            #pragma unroll
            for (int mt = 0; mt < 2; ++mt) {
                int row = wm*32 + mt*16 + col;
                int ck  = kc*4 + quad;
                int sz  = (ck & ~7) | ((ck ^ row) & 7);
                af[mt] = *(const v8h*)&xb[row*320 + sz*8];
            }
            #pragma unroll
            for (int mt = 0; mt < 2; ++mt)
                #pragma unroll
                for (int nt = 0; nt < 4; ++nt)
                    acc[mt][nt] = __builtin_amdgcn_mfma_f32_16x16x32_f16(
                        af[mt], bfr[nt][kc], acc[mt][nt], 0, 0, 0);
        }

        // 3. mid: retire g+ex staging regs, issue h gathers
        if (hn) { write_gx(nxt); issue_h(ca2); }

        // 4. second K half (kc 5..9)
        #pragma unroll
        for (int kc = 5; kc < 10; ++kc) {
            v8h af[2];
            #pragma unroll
            for (int mt = 0; mt < 2; ++mt) {
                int row = wm*32 + mt*16 + col;
                int ck  = kc*4 + quad;
                int sz  = (ck & ~7) | ((ck ^ row) & 7);
                af[mt] = *(const v8h*)&xb[row*320 + sz*8];
            }
            #pragma unroll
            for (int mt = 0; mt < 2; ++mt)
                #pragma unroll
                for (int nt = 0; nt < 4; ++nt)
                    acc[mt][nt] = __builtin_amdgcn_mfma_f32_16x16x32_f16(
                        af[mt], bfr[nt][kc], acc[mt][nt], 0, 0, 0);
        }

        // 5. epilogue: bias + leaky-relu + dot W2 over this lane's 4 n-cols
        {
            float* pb = part + cur*4096;
            #pragma unroll
            for (int mt = 0; mt < 2; ++mt) {
                v4f pv = (v4f){0.f,0.f,0.f,0.f};
                #pragma unroll
                for (int nt = 0; nt < 4; ++nt)
                    #pragma unroll
                    for (int r = 0; r < 4; ++r) {
                        float hv = acc[mt][nt][r] + b1v[nt];
                        hv = (hv > 0.f) ? hv : 0.01f * hv;
                        pv[r] += hv * w2v[nt];
                    }
                int P  = wn*16 + col;                 // n-col partial 0..63
                int Q  = wm*8 + mt*4 + quad;          // edge>>2
                int Qx = Q ^ col;
                *(v4f*)&pb[P*64 + Qx*4] = pv;
            }
        }

        // 6. retire h staging regs
        if (hn) write_h(nxt);

        __syncthreads();   // the ONLY barrier per tile

        // 7. reduction of part[cur]: 512 threads = 64 edges x 8 segs
        {
            const float* pr = part + cur*4096;
            int erow = tid >> 3, seg = tid & 7;
            int Q = erow >> 2, r = erow & 3;
            float v = 0.f;
            #pragma unroll
            for (int i = 0; i < 8; ++i) {
                int P  = (i << 3) | seg;
                int Qx = Q ^ (P & 15);
                v += pr[P*64 + Qx*4 + r];
            }
            v += __shfl_xor(v, 1, 8);
            v += __shfl_xor(v, 2, 8);
            v += __shfl_xor(v, 4, 8);
            if (seg == 0) {
                long eg = (t0 + ti)*64 + erow;
                if (eg < NEDGE) out[eg*14 + k14] = v + b2v;
            }
        }

        ca1 = fa1; ca2 = fa2; cdv = fdv;
    }
}

extern "C" void kernel_launch(void* const* d_in, const int* in_sizes, int n_in,
                              void* d_out, int out_size, void* d_ws, size_t ws_size,
                              hipStream_t stream)
{
    (void)in_sizes; (void)n_in; (void)out_size; (void)ws_size;
    const float* sfeat = (const float*)d_in[0];
    const float* pfeat = (const float*)d_in[1];
    const float* dfeat = (const float*)d_in[2];
    const float* Sfeat = (const float*)d_in[3];
    const int*   hop   = (const int*)  d_in[4];
    const float* darr  = (const float*)d_in[5];
    const float* exd   = (const float*)d_in[6];
    const float* W1    = (const float*)d_in[7];
    const float* b1    = (const float*)d_in[8];
    const float* W2    = (const float*)d_in[9];
    const float* b2    = (const float*)d_in[10];
    _Float16* W1T = (_Float16*)d_ws;   // 14*320*256*2 B = 2.29 MB

    static bool attr_done = false;
    if (!attr_done) {
        hipFuncSetAttribute((const void*)hopping_ws,
                            hipFuncAttributeMaxDynamicSharedMemorySize, 114688);
        attr_done = true;
    }

    // d_ws is re-poisoned before every timed call -> rebuild W1T every launch.
    prep_w1<<<dim3(4480), dim3(256), 0, stream>>>(W1, W1T);

    hopping_ws<<<dim3(NCH * NPAIR), dim3(512), 114688, stream>>>(
        sfeat, pfeat, dfeat, Sfeat, hop, darr, exd, b1, W2, b2, W1T, (float*)d_out);
}

// Round 9
// 2255.376 us; speedup vs baseline: 2.3020x; 2.3020x over previous
//
#include <hip/hip_runtime.h>

#define NEDGE  500000
#define NTILE  7813        // ceil(NEDGE/64)
#define NCH    280         // chunks (divisible by 8 XCDs: 35 per XCD)
#define CHUNK  28          // tiles per chunk; 280*28 = 7840 >= 7813
#define NPAIR  14

typedef _Float16 v8h __attribute__((ext_vector_type(8)));
typedef float    v4f __attribute__((ext_vector_type(4)));

// PAIRS in natural k order
__constant__ int cI[14] = {0,0,1,1,0,1,1,2,2,2,3,3,3,3};
__constant__ int cJ[14] = {0,1,1,1,2,2,2,2,2,2,3,0,1,2};

// W1 (14,320,256) fp32 -> W1T fp16 in MFMA-B-fragment tile order:
// W1T[k14][nt(16)][kc(10)][quad(4)][col(16)][j(8)]
__global__ __launch_bounds__(256) void prep_w1(const float* __restrict__ W1,
                                               _Float16* __restrict__ W1T) {
    int tid = blockIdx.x * 256 + threadIdx.x;
    if (tid >= 14*320*256) return;
    int n   = tid & 255;
    int t   = tid >> 8;
    int kk  = t % 320;
    int k14 = t / 320;
    float v = W1[tid];
    int dst = ((((k14*16 + (n>>4))*10 + (kk>>5))*4 + ((kk>>3)&3))*16 + (n&15))*8 + (kk&7);
    W1T[dst] = (_Float16)v;
}

// Dynamic LDS (bytes), sized for 2 blocks/CU (72 KB/block):
//   [     0, 40960)  xbuf[64*320] f16   (SINGLE X tile, swizzled)
//   [ 40960, 73728)  part[2][128*16] f32 (parity-buffered reduction scratch)
// X swizzle: 16B chunk ck at row -> ck' = (ck & ~7) | ((ck ^ row) & 7)
// part (per parity): written as v4f at word (P*16 + Qx*... ) -- layout:
//   P = w*16+col (0..127 n-col partial), Q = mt*4+quad (edge>>2, 0..15),
//   Qx = Q ^ (P & 15); word addr = P*16 + Qx  holds v4f? -> see code: stored
//   as 128 rows x 16 v4f-slots = 128*16*4 floats = 8192 floats (32 KB) per
//   parity is too big; so partial pre-reduced over nt in-lane (2 cols) keeps
//   P at 128 but we store only Qx slot -> 128*16 v4f = 8 KB? No: 128*16
//   v4f = 2048 v4f = 8192 floats = 32 KB. Budget: part total 32 KB = one
//   parity 16 KB = 128*16 v4f/4.. => store v4f at float-offset (P*16+Qx)*... 
//   Final: per parity 4096 floats = 16 KB: addr = (P*8 + (Qx&7))*4 + ... 
// REGISTER BUDGET (hard-won, rounds 6-8): 512-thread kernels get a 128-VGPR
// allocator budget on this toolchain regardless of launch-bounds/waves-per-eu
// -> designs needing >128 regs spill to scratch (6.5 GB writes, MfmaUtil 9%).
// So nt=2 B-residency (80 regs, ~116 total) + 2 blocks/CU for stall cover.
__global__ __launch_bounds__(512, 2) void hopping_ws(
    const float* __restrict__ sfeat, const float* __restrict__ pfeat,
    const float* __restrict__ dfeat, const float* __restrict__ Sfeat,
    const int*  __restrict__ hop,   const float* __restrict__ darr,
    const float* __restrict__ exd,  const float* __restrict__ b1,
    const float* __restrict__ W2,   const float* __restrict__ b2,
    const _Float16* __restrict__ W1T, float* __restrict__ out)
{
    extern __shared__ char smem[];
    _Float16* xb   = (_Float16*)smem;                 // 20480 halves (40 KB)
    float*    part = (float*)(smem + 40960);          // 2 x 4096 floats (32 KB)

    const int tid = threadIdx.x;          // 0..511
    const int bid = blockIdx.x;           // 0..3919

    const int xcd   = bid & 7;
    const int q     = bid >> 3;
    const int k14   = q % 14;
    const int chunk = xcd*35 + q/14;      // 0..279
    const long t0   = (long)chunk * CHUNK;
    int my_n = CHUNK;
    if (t0 + my_n > NTILE) my_n = (int)(NTILE - t0);   // always >= 1

    const int i4 = cI[k14], j4 = cJ[k14];
    const float* gt = (i4==0)?sfeat:(i4==1)?pfeat:(i4==2)?dfeat:Sfeat;
    const float* ht = (j4==0)?sfeat:(j4==1)?pfeat:(j4==2)?dfeat:Sfeat;

    const int lane = tid & 63;
    const int w    = tid >> 6;            // wave 0..7: owns cols [w*32, w*32+32)
    const int col  = lane & 15;
    const int quad = lane >> 4;
    const int ser  = tid >> 3;            // staging row 0..63
    const int sq   = tid & 7;             // 8 threads per row

    // ---- resident B fragments: 2 nt x 10 kc x b128 = 80 VGPRs, loaded once ----
    v8h bfr[2][10];
    {
        const _Float16* wb = W1T + (size_t)k14 * 81920;
        #pragma unroll
        for (int nt = 0; nt < 2; ++nt)
            #pragma unroll
            for (int kc = 0; kc < 10; ++kc)
                bfr[nt][kc] = *(const v8h*)&wb[(((size_t)(w*2+nt)*10 + kc)*64 + lane)*8];
    }
    float b1v[2], w2v[2];
    #pragma unroll
    for (int nt = 0; nt < 2; ++nt) {
        int n = (w*2+nt)*16 + col;
        b1v[nt] = b1[k14*256 + n];
        w2v[nt] = W2[k14*256 + n];
    }
    const float b2v = b2[k14];

    // ---- staging state ----
    float4 sg[4], sh[4], sx[2]; float sinv = 0.f;
    int ca1, ca2; float cdv;      // hop data for tile (ti+1)
    int fa1, fa2; float fdv;      // hop data for tile (ti+2)

    auto hopload = [&](int ti, int& a1, int& a2, float& dv) {
        long eg = (t0 + ti)*64 + ser; if (eg >= NEDGE) eg = NEDGE - 1;
        a1 = hop[2*eg]; a2 = hop[2*eg + 1]; dv = darr[eg];
    };
    auto issue_gx = [&](int ti, int a1, float dv) {
        sinv = 1.0f / (dv * dv);
        const float4* s1 = (const float4*)gt + (size_t)a1 * 32;
        #pragma unroll
        for (int r = 0; r < 4; ++r) sg[r] = s1[sq*4 + r];
        long eg = (t0 + ti)*64 + ser; if (eg >= NEDGE) eg = NEDGE - 1;
        const float4* s3 = (const float4*)exd + eg * 16;
        sx[0] = s3[sq*2]; sx[1] = s3[sq*2 + 1];
    };
    auto issue_h = [&](int a2) {
        const float4* s2 = (const float4*)ht + (size_t)a2 * 32;
        #pragma unroll
        for (int r = 0; r < 4; ++r) sh[r] = s2[sq*4 + r];
    };
    auto write_gx = [&]() {
        #pragma unroll
        for (int hf = 0; hf < 2; ++hf) {       // g chunks 2sq, 2sq+1
            float4 a = sg[hf*2], b = sg[hf*2+1];
            v8h hv;
            hv[0]=(_Float16)(a.x*sinv); hv[1]=(_Float16)(a.y*sinv);
            hv[2]=(_Float16)(a.z*sinv); hv[3]=(_Float16)(a.w*sinv);
            hv[4]=(_Float16)(b.x*sinv); hv[5]=(_Float16)(b.y*sinv);
            hv[6]=(_Float16)(b.z*sinv); hv[7]=(_Float16)(b.w*sinv);
            int ch = sq*2 + hf;
            int sz = (ch & ~7) | ((ch ^ ser) & 7);
            *(v8h*)&xb[ser*320 + sz*8] = hv;
        }
        {                                       // ex chunk 32+sq (no scaling)
            float4 a = sx[0], b = sx[1];
            v8h hv;
            hv[0]=(_Float16)a.x; hv[1]=(_Float16)a.y;
            hv[2]=(_Float16)a.z; hv[3]=(_Float16)a.w;
            hv[4]=(_Float16)b.x; hv[5]=(_Float16)b.y;
            hv[6]=(_Float16)b.z; hv[7]=(_Float16)b.w;
            int ch = 32 + sq;
            int sz = (ch & ~7) | ((ch ^ ser) & 7);
            *(v8h*)&xb[ser*320 + sz*8] = hv;
        }
    };
    auto write_h = [&]() {
        #pragma unroll
        for (int hf = 0; hf < 2; ++hf) {       // h chunks 16+2sq, 16+2sq+1
            float4 a = sh[hf*2], b = sh[hf*2+1];
            v8h hv;
            hv[0]=(_Float16)(a.x*sinv); hv[1]=(_Float16)(a.y*sinv);
            hv[2]=(_Float16)(a.z*sinv); hv[3]=(_Float16)(a.w*sinv);
            hv[4]=(_Float16)(b.x*sinv); hv[5]=(_Float16)(b.y*sinv);
            hv[6]=(_Float16)(b.z*sinv); hv[7]=(_Float16)(b.w*sinv);
            int ch = 16 + sq*2 + hf;
            int sz = (ch & ~7) | ((ch ^ ser) & 7);
            *(v8h*)&xb[ser*320 + sz*8] = hv;
        }
    };

    // ---- prologue: fill X for tile 0; prefetch hop for tile 1 ----
    {
        int a1, a2; float dv;
        hopload(0, a1, a2, dv);
        issue_gx(0, a1, dv);
        issue_h(a2);
        hopload(1, ca1, ca2, cdv);
        write_gx();
        write_h();
    }
    __syncthreads();

    #pragma unroll 1
    for (int ti = 0; ti < my_n; ++ti) {
        const int  cur = ti & 1;
        const bool hn  = (ti + 1 < my_n);

        // ---- phase 1 (X read-only) ----
        if (hn)              issue_gx(ti+1, ca1, cdv);
        if (ti + 2 < my_n)   hopload(ti+2, fa1, fa2, fdv);

        v4f acc[4][2];
        #pragma unroll
        for (int a = 0; a < 4; ++a) {
            acc[a][0] = (v4f){0.f,0.f,0.f,0.f};
            acc[a][1] = (v4f){0.f,0.f,0.f,0.f};
        }

        #pragma unroll
        for (int kc = 0; kc < 5; ++kc) {
            v8h af[4];
            #pragma unroll
            for (int mt = 0; mt < 4; ++mt) {
                int row = mt*16 + col;
                int ck  = kc*4 + quad;
                int sz  = (ck & ~7) | ((ck ^ row) & 7);
                af[mt] = *(const v8h*)&xb[row*320 + sz*8];
            }
            #pragma unroll
            for (int mt = 0; mt < 4; ++mt)
                #pragma unroll
                for (int nt = 0; nt < 2; ++nt)
                    acc[mt][nt] = __builtin_amdgcn_mfma_f32_16x16x32_f16(
                        af[mt], bfr[nt][kc], acc[mt][nt], 0, 0, 0);
        }

        if (hn) issue_h(ca2);   // h gathers in flight under second K half

        #pragma unroll
        for (int kc = 5; kc < 10; ++kc) {
            v8h af[4];
            #pragma unroll
            for (int mt = 0; mt < 4; ++mt) {
                int row = mt*16 + col;
                int ck  = kc*4 + quad;
                int sz  = (ck & ~7) | ((ck ^ row) & 7);
                af[mt] = *(const v8h*)&xb[row*320 + sz*8];
            }
            #pragma unroll
            for (int mt = 0; mt < 4; ++mt)
                #pragma unroll
                for (int nt = 0; nt < 2; ++nt)
                    acc[mt][nt] = __builtin_amdgcn_mfma_f32_16x16x32_f16(
                        af[mt], bfr[nt][kc], acc[mt][nt], 0, 0, 0);
        }

        // epilogue: bias + leaky-relu + dot W2 -> part[cur]
        // In-lane sum over nt(2 cols) -> P = w*8 + col&7?? NO: distinct cols
        // per wave pair. 8 waves x 16 lanescols = 128 col-partials, but cols
        // 0..15 of waves sharing the same 32-col group don't exist (each wave
        // distinct). To keep part at 64 P-entries (16 KB/parity), pre-pair
        // waves w and w^4 via the SAME slot with Q offset by 16:
        //   P = (w&3)*16 + col (0..63), Qslot = (w>>2)*16 + mt*4 + quad (0..31)
        //   word addr = P*64 + ((Qslot^P)&31)*... -> 64*32 v4f? too big.
        // Simplest correct: part per parity = 128 P x 16 Q x ... no.
        // FINAL (matches reduction below): per parity 4096 floats:
        //   addr = P2*64 + Qx*4 + r, P2 = (w&3)*16+col (0..63),
        //   Qx = (mt*4+quad) ^ P2lo, and waves w>=4 ADD into the same slots
        //   via LDS atomic-free two-pass: first w<4 write, then w>=4 add.
        {
            float* pb = part + cur*4096;
            #pragma unroll
            for (int mt = 0; mt < 4; ++mt) {
                v4f pv = (v4f){0.f,0.f,0.f,0.f};
                #pragma unroll
                for (int nt = 0; nt < 2; ++nt)
                    #pragma unroll
                    for (int r = 0; r < 4; ++r) {
                        float hv = acc[mt][nt][r] + b1v[nt];
                        hv = (hv > 0.f) ? hv : 0.01f * hv;
                        pv[r] += hv * w2v[nt];
                    }
                int P  = w*16 + col;                  // 0..127
                int Q  = mt*4 + quad;                 // 0..15
                int Qx = Q ^ (P & 15);
                // per parity: 128 P x 16 Q x ... needs 8192 floats; we have
                // 4096 -> pack v4f at half-resolution: store at
                // word = (P*16 + Qx) * 2  ... 128*16*2 = 4096 ✓ but v4f needs
                // 4 words. Use b64 pairs instead: split pv into two b64.
                float2* pb2 = (float2*)pb;
                pb2[(P*16 + Qx)] = make_float2(pv[0], pv[1]);
                // second half of edges in the OTHER parity bank region:
                ((float2*)(part + (cur^0)*0 + 8192))[(P*16 + Qx)] =
                    make_float2(pv[2], pv[3]);
            }
        }

        __syncthreads();   // barrier 1: X reads + part writes done

        // ---- phase 2: restage X, reduce part, store ----
        if (hn) { write_gx(); write_h(); }

        {
            // 512 threads: edge e = tid>>3 (0..63), seg = tid&7
            // value for edge e, P: e = Q*4+r -> Q = e>>2, r = e&3
            // pv[r] lives in pair (r<2 ? low-bank : high-bank) word r&1
            int e = tid >> 3, seg = tid & 7;
            int Q = e >> 2, r = e & 3;
            const float2* lo = (const float2*)(part + cur*4096);
            const float2* hi = (const float2*)(part + 8192);
            float v = 0.f;
            #pragma unroll
            for (int i = 0; i < 16; ++i) {
                int P  = seg*16 + i;                 // 0..127
                int Qx = Q ^ (P & 15);
                float2 pr = (r < 2) ? lo[P*16 + Qx] : hi[P*16 + Qx];
                v += (r & 1) ? pr.y : pr.x;
            }
            v += __shfl_xor(v, 1, 8);
            v += __shfl_xor(v, 2, 8);
            v += __shfl_xor(v, 4, 8);
            if (seg == 0) {
                long eg = (t0 + ti)*64 + e;
                if (eg < NEDGE) out[eg*14 + k14] = v + b2v;
            }
        }

        __syncthreads();   // barrier 2: X writes + part reads done

        ca1 = fa1; ca2 = fa2; cdv = fdv;
    }
}

extern "C" void kernel_launch(void* const* d_in, const int* in_sizes, int n_in,
                              void* d_out, int out_size, void* d_ws, size_t ws_size,
                              hipStream_t stream)
{
    (void)in_sizes; (void)n_in; (void)out_size; (void)ws_size;
    const float* sfeat = (const float*)d_in[0];
    const float* pfeat = (const float*)d_in[1];
    const float* dfeat = (const float*)d_in[2];
    const float* Sfeat = (const float*)d_in[3];
    const int*   hop   = (const int*)  d_in[4];
    const float* darr  = (const float*)d_in[5];
    const float* exd   = (const float*)d_in[6];
    const float* W1    = (const float*)d_in[7];
    const float* b1    = (const float*)d_in[8];
    const float* W2    = (const float*)d_in[9];
    const float* b2    = (const float*)d_in[10];
    _Float16* W1T = (_Float16*)d_ws;   // 14*320*256*2 B = 2.29 MB

    static bool attr_done = false;
    if (!attr_done) {
        hipFuncSetAttribute((const void*)hopping_ws,
                            hipFuncAttributeMaxDynamicSharedMemorySize, 90112);
        attr_done = true;
    }

    // d_ws is re-poisoned before every timed call -> rebuild W1T every launch.
    prep_w1<<<dim3(4480), dim3(256), 0, stream>>>(W1, W1T);

    hopping_ws<<<dim3(NCH * NPAIR), dim3(512), 90112, stream>>>(
        sfeat, pfeat, dfeat, Sfeat, hop, darr, exd, b1, W2, b2, W1T, (float*)d_out);
}